// Round 2
// baseline (843.466 us; speedup 1.0000x reference)
//
#include <hip/hip_runtime.h>
#include <hip/hip_bf16.h>

// Problem dims (fixed by reference)
#define BB 32
#define HH 3
#define MM 2048
#define DD 512
#define LL 32
#define TT 2049
#define NCHUNK 32          // m-chunks for weighted partials
#define MCHUNK (MM / NCHUNK)

// ---------------------------------------------------------------------------
// k1: u[b,d] = sum_l B_emb[query[b,l], d] * pos_enc[l, d]
// grid: BB blocks x 256 threads, each thread handles 2 consecutive d
// ---------------------------------------------------------------------------
__global__ __launch_bounds__(256) void qembed_kernel(
    const int* __restrict__ query, const float* __restrict__ B_emb,
    const float* __restrict__ pos_enc, float* __restrict__ u) {
    int b = blockIdx.x;
    int d0 = threadIdx.x * 2;
    float a0 = 0.f, a1 = 0.f;
#pragma unroll 4
    for (int l = 0; l < LL; ++l) {
        int q = query[b * LL + l];
        float2 e = *(const float2*)(B_emb + (size_t)q * DD + d0);
        float2 pe = *(const float2*)(pos_enc + l * DD + d0);
        a0 += e.x * pe.x;
        a1 += e.y * pe.y;
    }
    u[b * DD + d0] = a0;
    u[b * DD + d0 + 1] = a1;
}

// ---------------------------------------------------------------------------
// k2: logits[b,m] = dot(key_mems[b,hop,m,:] + TA[hop, rel_time[b,m], :], u[b,:])
// grid: (MM/4, BB), 256 threads = 4 waves, one wave per m. Lane covers 8 d's
// via two float4 loads (32 B/lane from each source).
// ---------------------------------------------------------------------------
__global__ __launch_bounds__(256) void logits_kernel(
    const float* __restrict__ key_mems, const float* __restrict__ TA,
    const int* __restrict__ rel_time, const float* __restrict__ u,
    float* __restrict__ logits, int hop) {
    int b = blockIdx.y;
    int wave = threadIdx.x >> 6;
    int lane = threadIdx.x & 63;
    int m = blockIdx.x * 4 + wave;
    int t = rel_time[b * MM + m];
    int d0 = lane * 8;

    const float* krow = key_mems + (((size_t)(b * HH + hop) * MM + m) * DD) + d0;
    const float* arow = TA + ((size_t)(hop * TT + t) * DD) + d0;
    const float* urow = u + b * DD + d0;

    float4 k0 = *(const float4*)krow;
    float4 k1 = *(const float4*)(krow + 4);
    float4 a0 = *(const float4*)arow;
    float4 a1 = *(const float4*)(arow + 4);
    float4 u0 = *(const float4*)urow;
    float4 u1 = *(const float4*)(urow + 4);

    float acc = (k0.x + a0.x) * u0.x + (k0.y + a0.y) * u0.y +
                (k0.z + a0.z) * u0.z + (k0.w + a0.w) * u0.w +
                (k1.x + a1.x) * u1.x + (k1.y + a1.y) * u1.y +
                (k1.z + a1.z) * u1.z + (k1.w + a1.w) * u1.w;

#pragma unroll
    for (int off = 32; off > 0; off >>= 1) acc += __shfl_xor(acc, off);
    if (lane == 0) logits[b * MM + m] = acc;
}

// ---------------------------------------------------------------------------
// k3: softmax over M per batch row, in place. grid: BB blocks x 256 threads.
// ---------------------------------------------------------------------------
__global__ __launch_bounds__(256) void softmax_kernel(float* __restrict__ logits) {
    __shared__ float sred[4];
    int b = blockIdx.x;
    float* row = logits + b * MM;
    int tid = threadIdx.x;
    int wave = tid >> 6, lane = tid & 63;

    float vals[8];
    float mx = -3.4e38f;
#pragma unroll
    for (int j = 0; j < 8; ++j) {
        vals[j] = row[j * 256 + tid];
        mx = fmaxf(mx, vals[j]);
    }
#pragma unroll
    for (int off = 32; off > 0; off >>= 1) mx = fmaxf(mx, __shfl_xor(mx, off));
    if (lane == 0) sred[wave] = mx;
    __syncthreads();
    mx = fmaxf(fmaxf(sred[0], sred[1]), fmaxf(sred[2], sred[3]));
    __syncthreads();

    float s = 0.f;
#pragma unroll
    for (int j = 0; j < 8; ++j) {
        vals[j] = expf(vals[j] - mx);
        s += vals[j];
    }
#pragma unroll
    for (int off = 32; off > 0; off >>= 1) s += __shfl_xor(s, off);
    if (lane == 0) sred[wave] = s;
    __syncthreads();
    s = (sred[0] + sred[1]) + (sred[2] + sred[3]);
    float inv = 1.f / s;
#pragma unroll
    for (int j = 0; j < 8; ++j) row[j * 256 + tid] = vals[j] * inv;
}

// ---------------------------------------------------------------------------
// k4: partials[c,b,d] = sum_{m in chunk c} (val_mems[b,hop,m,d] +
//                       TC[hop, rel_time[b,m], d]) * p[b,m]
// grid: (NCHUNK, BB). 256 threads = 4 waves; wave w handles m = base+4j+w.
// Lane covers 8 d's. LDS combine across the 4 waves.
// ---------------------------------------------------------------------------
__global__ __launch_bounds__(256) void weighted_kernel(
    const float* __restrict__ val_mems, const float* __restrict__ TC,
    const int* __restrict__ rel_time, const float* __restrict__ p,
    float* __restrict__ partials, int hop) {
    __shared__ float sm[4][DD];
    int b = blockIdx.y, c = blockIdx.x;
    int wave = threadIdx.x >> 6, lane = threadIdx.x & 63;
    int d0 = lane * 8;

    float acc[8] = {0.f, 0.f, 0.f, 0.f, 0.f, 0.f, 0.f, 0.f};
#pragma unroll 2
    for (int j = 0; j < MCHUNK / 4; ++j) {
        int m = c * MCHUNK + j * 4 + wave;
        float pw = p[b * MM + m];
        int t = rel_time[b * MM + m];
        const float* vrow =
            val_mems + (((size_t)(b * HH + hop) * MM + m) * DD) + d0;
        const float* crow = TC + ((size_t)(hop * TT + t) * DD) + d0;
        float4 v0 = *(const float4*)vrow;
        float4 v1 = *(const float4*)(vrow + 4);
        float4 c0 = *(const float4*)crow;
        float4 c1 = *(const float4*)(crow + 4);
        acc[0] += (v0.x + c0.x) * pw;
        acc[1] += (v0.y + c0.y) * pw;
        acc[2] += (v0.z + c0.z) * pw;
        acc[3] += (v0.w + c0.w) * pw;
        acc[4] += (v1.x + c1.x) * pw;
        acc[5] += (v1.y + c1.y) * pw;
        acc[6] += (v1.z + c1.z) * pw;
        acc[7] += (v1.w + c1.w) * pw;
    }
#pragma unroll
    for (int k = 0; k < 8; ++k) sm[wave][d0 + k] = acc[k];
    __syncthreads();
#pragma unroll
    for (int r = 0; r < 2; ++r) {
        int d = threadIdx.x * 2 + r;
        float s = (sm[0][d] + sm[1][d]) + (sm[2][d] + sm[3][d]);
        partials[((size_t)c * BB + b) * DD + d] = s;
    }
}

// ---------------------------------------------------------------------------
// k5: u[idx] += sum_c partials[c, idx]   (idx over B*D)
// ---------------------------------------------------------------------------
__global__ __launch_bounds__(256) void reduce_kernel(
    const float* __restrict__ partials, float* __restrict__ u) {
    int idx = blockIdx.x * 256 + threadIdx.x;
    float s = 0.f;
#pragma unroll
    for (int c = 0; c < NCHUNK; ++c) s += partials[(size_t)c * BB * DD + idx];
    u[idx] += s;
}

// ---------------------------------------------------------------------------
// k6: out = u (fp32 copy; out buffer is the reference's fp32 output)
// ---------------------------------------------------------------------------
__global__ __launch_bounds__(256) void out_kernel(const float* __restrict__ u,
                                                 float* __restrict__ out) {
    int idx = blockIdx.x * 256 + threadIdx.x;
    out[idx] = u[idx];
}

extern "C" void kernel_launch(void* const* d_in, const int* in_sizes, int n_in,
                              void* d_out, int out_size, void* d_ws, size_t ws_size,
                              hipStream_t stream) {
    const int* query = (const int*)d_in[0];
    const int* rel_time = (const int*)d_in[1];
    const float* key_mems = (const float*)d_in[2];
    const float* val_mems = (const float*)d_in[3];
    const float* B_emb = (const float*)d_in[4];
    const float* TA = (const float*)d_in[5];
    const float* TC = (const float*)d_in[6];
    const float* pos_enc = (const float*)d_in[7];
    float* out = (float*)d_out;

    float* ws = (float*)d_ws;
    float* u = ws;                         // B*D            = 16384 floats
    float* logits = ws + BB * DD;          // B*M            = 65536 floats
    float* partials = logits + BB * MM;    // NCHUNK*B*D     = 524288 floats

    qembed_kernel<<<BB, 256, 0, stream>>>(query, B_emb, pos_enc, u);

    for (int hop = 0; hop < HH; ++hop) {
        logits_kernel<<<dim3(MM / 4, BB), 256, 0, stream>>>(
            key_mems, TA, rel_time, u, logits, hop);
        softmax_kernel<<<BB, 256, 0, stream>>>(logits);
        weighted_kernel<<<dim3(NCHUNK, BB), 256, 0, stream>>>(
            val_mems, TC, rel_time, logits, partials, hop);
        reduce_kernel<<<BB * DD / 256, 256, 0, stream>>>(partials, u);
    }

    out_kernel<<<BB * DD / 256, 256, 0, stream>>>(u, out);
}